// Round 4
// baseline (1400.654 us; speedup 1.0000x reference)
//
#include <hip/hip_runtime.h>
#include <hip/hip_bf16.h>

// Sizes
#define B_ 256
#define D_ 3072
#define H_ 256
#define OPT_ 32
#define OD_ 98304       // OPT_*D_
#define NL_ 4

typedef __attribute__((ext_vector_type(8))) short short8;
typedef __attribute__((ext_vector_type(4))) float f32x4;

__device__ __forceinline__ unsigned short f2bf(float f) {
    unsigned int u = __float_as_uint(f);
    unsigned int r = (u + 0x7FFFu + ((u >> 16) & 1u)) >> 16;
    return (unsigned short)r;
}

// ---------------------------------------------------------------------------
// init: cur = 0, rx = -x, zpart = 0  (grid 4096 x 256 = 1048576 threads)
__global__ __launch_bounds__(256) void init_kernel(const float* __restrict__ x,
                                                   float* __restrict__ cur,
                                                   float* __restrict__ rx,
                                                   float* __restrict__ zpart) {
    int gid = blockIdx.x * 256 + threadIdx.x;
    if (gid < B_ * D_) {
        cur[gid] = 0.f;
        rx[gid] = -x[gid];
    }
    zpart[gid] = 0.f;   // 16*B_*H_ = 1048576 exactly
}

// ---------------------------------------------------------------------------
// gemm1: zpart[ks][b][h] = sum_{d in 192-slice ks} cur[b][d] * Wb[d][h]
// grid 512 blocks (16 kslices x 32 bgroups of 8 b), 256 threads (= h)
__global__ __launch_bounds__(256) void gemm1_kernel(const float* __restrict__ cur,
                                                    const float* __restrict__ Wb,
                                                    float* __restrict__ zpart) {
    int t = threadIdx.x;
    int ks = blockIdx.x >> 5;     // 0..15
    int bg = blockIdx.x & 31;     // 0..31
    const float* wp = Wb + (size_t)ks * 192 * H_ + t;
    const float* cp = cur + (size_t)(bg * 8) * D_ + ks * 192;
    float acc[8] = {0.f, 0.f, 0.f, 0.f, 0.f, 0.f, 0.f, 0.f};
#pragma unroll 4
    for (int dd = 0; dd < 192; ++dd) {
        float w = wp[(size_t)dd * H_];
#pragma unroll
        for (int g = 0; g < 8; ++g) acc[g] += cp[(size_t)g * D_ + dd] * w;
    }
#pragma unroll
    for (int g = 0; g < 8; ++g)
        zpart[ks * (B_ * H_) + (bg * 8 + g) * H_ + t] = acc[g];
}

// ---------------------------------------------------------------------------
// E: base = relu(sum_ks zpart + bb). Writes bf16 staging image + f32 basef.
__global__ __launch_bounds__(256) void e_kernel(const float* __restrict__ zpart,
                                                const float* __restrict__ bb,
                                                unsigned char* __restrict__ base_ready,
                                                float* __restrict__ basef) {
    int m = blockIdx.x, k = threadIdx.x;
    float z = bb[k];
#pragma unroll
    for (int ks = 0; ks < 16; ++ks) z += zpart[ks * (B_ * H_) + m * H_ + k];
    z = z > 0.f ? z : 0.f;
    *(unsigned short*)(base_ready + (k >> 5) * 20480 + m * 80 + (k & 31) * 2) = f2bf(z);
    basef[m * H_ + k] = z;
}

// ---------------------------------------------------------------------------
// G2: fused GEMM (256x98304, K=256, bf16 MFMA) + squared-loss partials.
// (unchanged for attribution)
__global__ __launch_bounds__(512, 4) void g2_kernel(const unsigned char* __restrict__ base_ready,
                                                    const float* __restrict__ Wo,    // [256][98304] layer slice
                                                    const float* __restrict__ biasL, // [32*3072]
                                                    const float* __restrict__ boL,   // [98304]
                                                    const float* __restrict__ rx,    // [256*3072]
                                                    float* __restrict__ partial) {
    __shared__ __align__(16) unsigned char ldsA[2][20480];  // [m][32k bf16 + pad]
    __shared__ __align__(16) unsigned char ldsW[2][10240];  // [n][32k bf16 + pad]

    int t = threadIdx.x;
    int lane = t & 63, wv = t >> 6;
    int bx = blockIdx.x;
    int ncol0 = bx * 128;
    int o = bx / 24;                 // 24 blocks per option
    int dbase = (bx % 24) * 128;

    int wm = wv >> 1, wn = wv & 1;
    int lrow = lane & 15, lk = lane >> 4;
    int nW = t & 127, kq = t >> 7;   // W staging role: kq in 0..3

    f32x4 acc[4][4];
#pragma unroll
    for (int mi = 0; mi < 4; ++mi)
#pragma unroll
        for (int ni = 0; ni < 4; ++ni) acc[mi][ni] = 0.f;

    uint4 pa0, pa1, pa2;
    float wf[8];

#define LOADA(S) { const unsigned char* gA = base_ready + (S) * 20480;           \
    pa0 = *(const uint4*)(gA + t * 16);                                          \
    pa1 = *(const uint4*)(gA + 8192 + t * 16);                                   \
    if (t < 256) pa2 = *(const uint4*)(gA + 16384 + t * 16); }

#define LOADW(S) {                                                               \
    const float* gp0 = Wo + (size_t)((S) * 32 + kq * 4) * OD_ + ncol0 + nW;      \
    wf[0] = gp0[0]; wf[1] = gp0[OD_]; wf[2] = gp0[2 * OD_]; wf[3] = gp0[3 * OD_];\
    const float* gp1 = gp0 + (size_t)16 * OD_;                                   \
    wf[4] = gp1[0]; wf[5] = gp1[OD_]; wf[6] = gp1[2 * OD_]; wf[7] = gp1[3 * OD_]; }

#define WRITEA(BUF) {                                                            \
    *(uint4*)(ldsA[BUF] + t * 16) = pa0;                                         \
    *(uint4*)(ldsA[BUF] + 8192 + t * 16) = pa1;                                  \
    if (t < 256) *(uint4*)(ldsA[BUF] + 16384 + t * 16) = pa2; }

#define WRITEW(BUF) {                                                            \
    uint2 pk0, pk1;                                                              \
    pk0.x = (unsigned)f2bf(wf[0]) | ((unsigned)f2bf(wf[1]) << 16);               \
    pk0.y = (unsigned)f2bf(wf[2]) | ((unsigned)f2bf(wf[3]) << 16);               \
    *(uint2*)(ldsW[BUF] + nW * 80 + kq * 8) = pk0;                               \
    pk1.x = (unsigned)f2bf(wf[4]) | ((unsigned)f2bf(wf[5]) << 16);               \
    pk1.y = (unsigned)f2bf(wf[6]) | ((unsigned)f2bf(wf[7]) << 16);               \
    *(uint2*)(ldsW[BUF] + nW * 80 + 32 + kq * 8) = pk1; }

    LOADA(0); LOADW(0);
    WRITEA(0); WRITEW(0);
    __syncthreads();
    LOADA(1); LOADW(1);

    for (int s = 0; s < 8; ++s) {
        int cur = s & 1;
        short8 bfr[4];
#pragma unroll
        for (int ni = 0; ni < 4; ++ni) {
            int nn = wn * 64 + ni * 16 + lrow;
            bfr[ni] = *(const short8*)(ldsW[cur] + nn * 80 + lk * 16);
        }
#pragma unroll
        for (int mi = 0; mi < 4; ++mi) {
            int row = wm * 64 + mi * 16 + lrow;
            short8 af = *(const short8*)(ldsA[cur] + row * 80 + lk * 16);
#pragma unroll
            for (int ni = 0; ni < 4; ++ni)
                acc[mi][ni] = __builtin_amdgcn_mfma_f32_16x16x32_bf16(af, bfr[ni], acc[mi][ni], 0, 0, 0);
        }
        if (s < 7) { WRITEA(cur ^ 1); WRITEW(cur ^ 1); }
        __syncthreads();
        if (s < 6) { LOADA(s + 2); LOADW(s + 2); }
    }

#undef LOADA
#undef LOADW
#undef WRITEA
#undef WRITEW

    float q[4];
#pragma unroll
    for (int ni = 0; ni < 4; ++ni) {
        int dcol = dbase + wn * 64 + ni * 16 + lrow;
        q[ni] = biasL[o * D_ + dcol] + boL[o * D_ + dcol];
    }
    float ssum[4][4];
#pragma unroll
    for (int mi = 0; mi < 4; ++mi)
#pragma unroll
        for (int r = 0; r < 4; ++r) ssum[mi][r] = 0.f;

#pragma unroll
    for (int mi = 0; mi < 4; ++mi) {
#pragma unroll
        for (int ni = 0; ni < 4; ++ni) {
            int dcol = dbase + wn * 64 + ni * 16 + lrow;
#pragma unroll
            for (int r = 0; r < 4; ++r) {
                int rowm = wm * 64 + mi * 16 + lk * 4 + r;
                float tv = acc[mi][ni][r] + rx[rowm * D_ + dcol] + q[ni];
                ssum[mi][r] += tv * tv;
            }
        }
    }
#pragma unroll
    for (int mi = 0; mi < 4; ++mi)
#pragma unroll
        for (int r = 0; r < 4; ++r) {
            float v = ssum[mi][r];
            v += __shfl_xor(v, 1);
            v += __shfl_xor(v, 2);
            v += __shfl_xor(v, 4);
            v += __shfl_xor(v, 8);
            if (lrow == 0) {
                int rowm = wm * 64 + mi * 16 + lk * 4 + r;
                partial[(rowm * OPT_ + o) * 48 + (bx % 24) * 2 + wn] = v;
            }
        }
}

// ---------------------------------------------------------------------------
// C: per-b argmin over 32 options (tie-break lowest index = jnp.argmin).
__global__ __launch_bounds__(256) void c_kernel(const float* __restrict__ partial,
                                                int* __restrict__ idxbuf,
                                                float* __restrict__ enc, int layer) {
    __shared__ float ls[32];
    int b = blockIdx.x, t = threadIdx.x;
    int oo = t >> 3, j8 = t & 7;
    const float* pp = partial + (b * OPT_ + oo) * 48;
    float v = 0.f;
#pragma unroll
    for (int j = 0; j < 6; ++j) v += pp[j8 + 8 * j];
    v += __shfl_xor(v, 1);
    v += __shfl_xor(v, 2);
    v += __shfl_xor(v, 4);
    if (j8 == 0) ls[oo] = v;
    __syncthreads();
    if (t < 32) {
        float mv = ls[t];
        int mi = t;
#pragma unroll
        for (int m = 16; m >= 1; m >>= 1) {
            float ov = __shfl_xor(mv, m);
            int oi = __shfl_xor(mi, m);
            if (ov < mv || (ov == mv && oi < mi)) { mv = ov; mi = oi; }
        }
        if (t == 0) {
            idxbuf[b] = mi;
            enc[b * NL_ + layer] = (float)mi;
        }
    }
}

// ---------------------------------------------------------------------------
// BUCKET: single block, invert idxbuf (b -> o) into per-option lists (o -> b's).
__global__ __launch_bounds__(256) void bucket_kernel(const int* __restrict__ idxbuf,
                                                     int* __restrict__ ocount,
                                                     int* __restrict__ olist) {
    __shared__ int lcnt[32];
    int t = threadIdx.x;
    if (t < 32) lcnt[t] = 0;
    __syncthreads();
    int o = idxbuf[t];                 // t = b
    int pos = atomicAdd(&lcnt[o], 1);
    olist[o * 256 + pos] = t;
    __syncthreads();
    if (t < 32) ocount[t] = lcnt[t];
}

// ---------------------------------------------------------------------------
// D: recompute selected option per OPTION bucket, CHUNK-PARALLEL + LDS base.
// grid (32 o x 12 dt x 32 chunks), 256 threads (= d within 256-wide tile).
// Round-3 pathology: 64 per-lane GLOBAL broadcast base loads/k0-iter shared
// vmcnt with 384KB-strided w loads -> serialized latency (267 us, VALU 2%).
// Fix: stage the 8 base rows in LDS (lgkm counter, b128 broadcasts) and
// batch w loads 8-wide with 1-iter register prefetch so 8 independent
// global loads are always in flight under LDS+FMA work.
__global__ __launch_bounds__(256) void d_kernel(const int* __restrict__ ocount,
                                                const int* __restrict__ olist,
                                                const float* __restrict__ basef,
                                                const float* __restrict__ Wo,
                                                const float* __restrict__ boL,
                                                const float* __restrict__ biasL,
                                                const float* __restrict__ x,
                                                float* __restrict__ cur,
                                                float* __restrict__ rx) {
    __shared__ float basL[8][256];
    int t = threadIdx.x;
    int o = blockIdx.x, dt = blockIdx.y, chunk = blockIdx.z;
    int cnt = ocount[o];
    int c0 = chunk * 8;
    if (c0 >= cnt) return;          // uniform exit, before any __syncthreads
    int rem = cnt - c0;
    if (rem > 8) rem = 8;

    int bidx[8];
#pragma unroll
    for (int g = 0; g < 8; ++g) {
        int j = c0 + g;
        if (j >= cnt) j = cnt - 1;   // pad with duplicate (not written back)
        bidx[g] = olist[o * 256 + j];
    }
    // stage base rows: coalesced 1KB per row, conflict-free LDS writes
#pragma unroll
    for (int g = 0; g < 8; ++g) basL[g][t] = basef[bidx[g] * H_ + t];
    __syncthreads();

    int d = dt * 256 + t;
    const float* wp = Wo + (size_t)o * D_ + d;
    size_t nn = (size_t)o * D_ + d;
    float bov = boL[nn];
    float biv = biasL[nn];

    float acc[8] = {0.f, 0.f, 0.f, 0.f, 0.f, 0.f, 0.f, 0.f};
    float wreg[8];
#pragma unroll
    for (int u = 0; u < 8; ++u) wreg[u] = wp[(size_t)u * OD_];

    for (int k0 = 0; k0 < 256; k0 += 8) {
        float wcur[8];
#pragma unroll
        for (int u = 0; u < 8; ++u) wcur[u] = wreg[u];
        if (k0 + 8 < 256) {          // guard: stay inside this layer's slice
#pragma unroll
            for (int u = 0; u < 8; ++u) wreg[u] = wp[(size_t)(k0 + 8 + u) * OD_];
        }
#pragma unroll
        for (int h = 0; h < 2; ++h) {
            int kb = k0 + h * 4;
            f32x4 bv[8];
#pragma unroll
            for (int g = 0; g < 8; ++g) bv[g] = *(const f32x4*)&basL[g][kb];
#pragma unroll
            for (int u = 0; u < 4; ++u) {
                float wu = wcur[h * 4 + u];
#pragma unroll
                for (int g = 0; g < 8; ++g) acc[g] += bv[g][u] * wu;   // k ascending
            }
        }
    }
#pragma unroll
    for (int g = 0; g < 8; ++g) {
        if (g < rem) {
            int b = bidx[g];
            float outv = cur[b * D_ + d] + acc[g] + bov + biv;
            cur[b * D_ + d] = outv;
            rx[b * D_ + d] = outv - x[b * D_ + d];
        }
    }
}

// ---------------------------------------------------------------------------
extern "C" void kernel_launch(void* const* d_in, const int* in_sizes, int n_in,
                              void* d_out, int out_size, void* d_ws, size_t ws_size,
                              hipStream_t stream) {
    const float* x    = (const float*)d_in[0];  // [256][3072]
    const float* Wb   = (const float*)d_in[1];  // [3072][256]
    const float* bb   = (const float*)d_in[2];  // [256]
    const float* Wo   = (const float*)d_in[3];  // [4][256][98304]
    const float* bo   = (const float*)d_in[4];  // [4][98304]
    const float* bias = (const float*)d_in[5];  // [4][32][3072]

    float* out = (float*)d_out;
    float* enc = out;            // [256][4] (indices as float)
    float* cur = out + 1024;     // [256][3072] reconstruction

    float* ws = (float*)d_ws;
    float* zpart   = ws;                          // 16*256*256 = 1048576
    float* partial = ws + 1048576;                // 256*32*48  = 393216
    float* rx      = ws + 1441792;                // 256*3072   = 786432
    float* basef   = ws + 2228224;                // 256*256    = 65536
    unsigned char* base_ready = (unsigned char*)(ws + 2293760);  // 163840 B
    int* idxbuf    = (int*)(ws + 2334720);        // 256 ints
    int* ocount    = (int*)(ws + 2334976);        // 32 ints
    int* olist     = (int*)(ws + 2335008);        // 32*256 ints

    init_kernel<<<4096, 256, 0, stream>>>(x, cur, rx, zpart);

    for (int i = 0; i < NL_; ++i) {
        const float* WoL   = Wo + (size_t)i * H_ * OD_;
        const float* boLp  = bo + (size_t)i * OD_;
        const float* biasL = bias + (size_t)i * OD_;
        if (i > 0) gemm1_kernel<<<512, 256, 0, stream>>>(cur, Wb, zpart);
        e_kernel<<<256, 256, 0, stream>>>(zpart, bb, base_ready, basef);
        g2_kernel<<<768, 512, 0, stream>>>(base_ready, WoL, biasL, boLp, rx, partial);
        c_kernel<<<256, 256, 0, stream>>>(partial, idxbuf, enc, i);
        bucket_kernel<<<1, 256, 0, stream>>>(idxbuf, ocount, olist);
        d_kernel<<<dim3(32, 12, 32), 256, 0, stream>>>(ocount, olist, basef, WoL, boLp, biasL, x, cur, rx);
    }
}

// Round 5
// 419.011 us; speedup vs baseline: 3.3428x; 3.3428x over previous
//
#include <hip/hip_runtime.h>
#include <hip/hip_bf16.h>

// Sizes
#define B_ 256
#define D_ 3072
#define H_ 256
#define OPT_ 32
#define OD_ 98304       // OPT_*D_
#define NL_ 4

typedef __attribute__((ext_vector_type(8))) short short8;
typedef __attribute__((ext_vector_type(4))) float f32x4;

__device__ __forceinline__ unsigned short f2bf(float f) {
    unsigned int u = __float_as_uint(f);
    unsigned int r = (u + 0x7FFFu + ((u >> 16) & 1u)) >> 16;
    return (unsigned short)r;
}

// ---------------------------------------------------------------------------
// init: cur = 0, rx = -x, zpart = 0.  Grid 512 blocks, grid-stride (the old
// 4096-block grid cost ~90 us of pure block-drain at ~22 ns/block).
__global__ __launch_bounds__(256) void init_kernel(const float* __restrict__ x,
                                                   float* __restrict__ cur,
                                                   float* __restrict__ rx,
                                                   float* __restrict__ zpart) {
    int gid0 = blockIdx.x * 256 + threadIdx.x;   // 131072 threads
    for (int g = gid0; g < B_ * D_; g += 131072) {
        cur[g] = 0.f;
        rx[g] = -x[g];
    }
    for (int g = gid0; g < 16 * B_ * H_; g += 131072) zpart[g] = 0.f;
}

// ---------------------------------------------------------------------------
// gemm1: zpart[ks][b][h] = sum_{d in 192-slice ks} cur[b][d] * Wb[d][h]
// grid 512 blocks (16 kslices x 32 bgroups of 8 b), 256 threads (= h)
__global__ __launch_bounds__(256) void gemm1_kernel(const float* __restrict__ cur,
                                                    const float* __restrict__ Wb,
                                                    float* __restrict__ zpart) {
    int t = threadIdx.x;
    int ks = blockIdx.x >> 5;     // 0..15
    int bg = blockIdx.x & 31;     // 0..31
    const float* wp = Wb + (size_t)ks * 192 * H_ + t;
    const float* cp = cur + (size_t)(bg * 8) * D_ + ks * 192;
    float acc[8] = {0.f, 0.f, 0.f, 0.f, 0.f, 0.f, 0.f, 0.f};
#pragma unroll 4
    for (int dd = 0; dd < 192; ++dd) {
        float w = wp[(size_t)dd * H_];
#pragma unroll
        for (int g = 0; g < 8; ++g) acc[g] += cp[(size_t)g * D_ + dd] * w;
    }
#pragma unroll
    for (int g = 0; g < 8; ++g)
        zpart[ks * (B_ * H_) + (bg * 8 + g) * H_ + t] = acc[g];
}

// ---------------------------------------------------------------------------
// E: base = relu(sum_ks zpart + bb). Writes bf16 staging image + f32 basef.
__global__ __launch_bounds__(256) void e_kernel(const float* __restrict__ zpart,
                                                const float* __restrict__ bb,
                                                unsigned char* __restrict__ base_ready,
                                                float* __restrict__ basef) {
    int m = blockIdx.x, k = threadIdx.x;
    float z = bb[k];
#pragma unroll
    for (int ks = 0; ks < 16; ++ks) z += zpart[ks * (B_ * H_) + m * H_ + k];
    z = z > 0.f ? z : 0.f;
    *(unsigned short*)(base_ready + (k >> 5) * 20480 + m * 80 + (k & 31) * 2) = f2bf(z);
    basef[m * H_ + k] = z;
}

// ---------------------------------------------------------------------------
// G2: fused GEMM (256x98304, K=256, bf16 MFMA) + squared-loss partials.
// (unchanged for attribution)
__global__ __launch_bounds__(512, 4) void g2_kernel(const unsigned char* __restrict__ base_ready,
                                                    const float* __restrict__ Wo,    // [256][98304] layer slice
                                                    const float* __restrict__ biasL, // [32*3072]
                                                    const float* __restrict__ boL,   // [98304]
                                                    const float* __restrict__ rx,    // [256*3072]
                                                    float* __restrict__ partial) {
    __shared__ __align__(16) unsigned char ldsA[2][20480];  // [m][32k bf16 + pad]
    __shared__ __align__(16) unsigned char ldsW[2][10240];  // [n][32k bf16 + pad]

    int t = threadIdx.x;
    int lane = t & 63, wv = t >> 6;
    int bx = blockIdx.x;
    int ncol0 = bx * 128;
    int o = bx / 24;                 // 24 blocks per option
    int dbase = (bx % 24) * 128;

    int wm = wv >> 1, wn = wv & 1;
    int lrow = lane & 15, lk = lane >> 4;
    int nW = t & 127, kq = t >> 7;   // W staging role: kq in 0..3

    f32x4 acc[4][4];
#pragma unroll
    for (int mi = 0; mi < 4; ++mi)
#pragma unroll
        for (int ni = 0; ni < 4; ++ni) acc[mi][ni] = 0.f;

    uint4 pa0, pa1, pa2;
    float wf[8];

#define LOADA(S) { const unsigned char* gA = base_ready + (S) * 20480;           \
    pa0 = *(const uint4*)(gA + t * 16);                                          \
    pa1 = *(const uint4*)(gA + 8192 + t * 16);                                   \
    if (t < 256) pa2 = *(const uint4*)(gA + 16384 + t * 16); }

#define LOADW(S) {                                                               \
    const float* gp0 = Wo + (size_t)((S) * 32 + kq * 4) * OD_ + ncol0 + nW;      \
    wf[0] = gp0[0]; wf[1] = gp0[OD_]; wf[2] = gp0[2 * OD_]; wf[3] = gp0[3 * OD_];\
    const float* gp1 = gp0 + (size_t)16 * OD_;                                   \
    wf[4] = gp1[0]; wf[5] = gp1[OD_]; wf[6] = gp1[2 * OD_]; wf[7] = gp1[3 * OD_]; }

#define WRITEA(BUF) {                                                            \
    *(uint4*)(ldsA[BUF] + t * 16) = pa0;                                         \
    *(uint4*)(ldsA[BUF] + 8192 + t * 16) = pa1;                                  \
    if (t < 256) *(uint4*)(ldsA[BUF] + 16384 + t * 16) = pa2; }

#define WRITEW(BUF) {                                                            \
    uint2 pk0, pk1;                                                              \
    pk0.x = (unsigned)f2bf(wf[0]) | ((unsigned)f2bf(wf[1]) << 16);               \
    pk0.y = (unsigned)f2bf(wf[2]) | ((unsigned)f2bf(wf[3]) << 16);               \
    *(uint2*)(ldsW[BUF] + nW * 80 + kq * 8) = pk0;                               \
    pk1.x = (unsigned)f2bf(wf[4]) | ((unsigned)f2bf(wf[5]) << 16);               \
    pk1.y = (unsigned)f2bf(wf[6]) | ((unsigned)f2bf(wf[7]) << 16);               \
    *(uint2*)(ldsW[BUF] + nW * 80 + 32 + kq * 8) = pk1; }

    LOADA(0); LOADW(0);
    WRITEA(0); WRITEW(0);
    __syncthreads();
    LOADA(1); LOADW(1);

    for (int s = 0; s < 8; ++s) {
        int cur = s & 1;
        short8 bfr[4];
#pragma unroll
        for (int ni = 0; ni < 4; ++ni) {
            int nn = wn * 64 + ni * 16 + lrow;
            bfr[ni] = *(const short8*)(ldsW[cur] + nn * 80 + lk * 16);
        }
#pragma unroll
        for (int mi = 0; mi < 4; ++mi) {
            int row = wm * 64 + mi * 16 + lrow;
            short8 af = *(const short8*)(ldsA[cur] + row * 80 + lk * 16);
#pragma unroll
            for (int ni = 0; ni < 4; ++ni)
                acc[mi][ni] = __builtin_amdgcn_mfma_f32_16x16x32_bf16(af, bfr[ni], acc[mi][ni], 0, 0, 0);
        }
        if (s < 7) { WRITEA(cur ^ 1); WRITEW(cur ^ 1); }
        __syncthreads();
        if (s < 6) { LOADA(s + 2); LOADW(s + 2); }
    }

#undef LOADA
#undef LOADW
#undef WRITEA
#undef WRITEW

    float q[4];
#pragma unroll
    for (int ni = 0; ni < 4; ++ni) {
        int dcol = dbase + wn * 64 + ni * 16 + lrow;
        q[ni] = biasL[o * D_ + dcol] + boL[o * D_ + dcol];
    }
    float ssum[4][4];
#pragma unroll
    for (int mi = 0; mi < 4; ++mi)
#pragma unroll
        for (int r = 0; r < 4; ++r) ssum[mi][r] = 0.f;

#pragma unroll
    for (int mi = 0; mi < 4; ++mi) {
#pragma unroll
        for (int ni = 0; ni < 4; ++ni) {
            int dcol = dbase + wn * 64 + ni * 16 + lrow;
#pragma unroll
            for (int r = 0; r < 4; ++r) {
                int rowm = wm * 64 + mi * 16 + lk * 4 + r;
                float tv = acc[mi][ni][r] + rx[rowm * D_ + dcol] + q[ni];
                ssum[mi][r] += tv * tv;
            }
        }
    }
#pragma unroll
    for (int mi = 0; mi < 4; ++mi)
#pragma unroll
        for (int r = 0; r < 4; ++r) {
            float v = ssum[mi][r];
            v += __shfl_xor(v, 1);
            v += __shfl_xor(v, 2);
            v += __shfl_xor(v, 4);
            v += __shfl_xor(v, 8);
            if (lrow == 0) {
                int rowm = wm * 64 + mi * 16 + lk * 4 + r;
                partial[(rowm * OPT_ + o) * 48 + (bx % 24) * 2 + wn] = v;
            }
        }
}

// ---------------------------------------------------------------------------
// C: per-b argmin over 32 options (tie-break lowest index = jnp.argmin).
__global__ __launch_bounds__(256) void c_kernel(const float* __restrict__ partial,
                                                int* __restrict__ idxbuf,
                                                float* __restrict__ enc, int layer) {
    __shared__ float ls[32];
    int b = blockIdx.x, t = threadIdx.x;
    int oo = t >> 3, j8 = t & 7;
    const float* pp = partial + (b * OPT_ + oo) * 48;
    float v = 0.f;
#pragma unroll
    for (int j = 0; j < 6; ++j) v += pp[j8 + 8 * j];
    v += __shfl_xor(v, 1);
    v += __shfl_xor(v, 2);
    v += __shfl_xor(v, 4);
    if (j8 == 0) ls[oo] = v;
    __syncthreads();
    if (t < 32) {
        float mv = ls[t];
        int mi = t;
#pragma unroll
        for (int m = 16; m >= 1; m >>= 1) {
            float ov = __shfl_xor(mv, m);
            int oi = __shfl_xor(mi, m);
            if (ov < mv || (ov == mv && oi < mi)) { mv = ov; mi = oi; }
        }
        if (t == 0) {
            idxbuf[b] = mi;
            enc[b * NL_ + layer] = (float)mi;
        }
    }
}

// ---------------------------------------------------------------------------
// BUCKET: single block. Inverts idxbuf into per-option lists AND emits a
// COMPACT work list: work[j] = (o<<8)|chunk for every non-empty chunk of 8.
// 32 <= nitems <= 60 (sum of ceil(cnt_o/8)); nitems stored in work[63].
__global__ __launch_bounds__(256) void bucket_kernel(const int* __restrict__ idxbuf,
                                                     int* __restrict__ ocount,
                                                     int* __restrict__ olist,
                                                     int* __restrict__ work) {
    __shared__ int lcnt[32];
    int t = threadIdx.x;
    if (t < 32) lcnt[t] = 0;
    __syncthreads();
    int o = idxbuf[t];                 // t = b
    int pos = atomicAdd(&lcnt[o], 1);
    olist[o * 256 + pos] = t;
    __syncthreads();
    if (t < 32) ocount[t] = lcnt[t];
    if (t == 0) {
        int n = 0;
        for (int oo = 0; oo < 32; ++oo) {
            int c = lcnt[oo];
            for (int ch = 0; ch * 8 < c; ++ch) work[n++] = (oo << 8) | ch;
        }
        work[63] = n;
    }
}

// ---------------------------------------------------------------------------
// D: recompute selected option, driven by the COMPACT work list.
// grid (32 x 12) = 384 blocks -- NO empty blocks (rounds 3/4 launched 12288
// blocks; the ~12k empties drained at ~22 ns/block = ~270 us of pure block
// issue/retire, starving the 384 active blocks). Each block handles work
// items j = bx, bx+32 (<=2). Inner loop: LDS-staged base rows (broadcast
// b128 reads) + 8-wide w batches; k-ascending FMA order (numerics identical).
__global__ __launch_bounds__(256) void d_kernel(const int* __restrict__ work,
                                                const int* __restrict__ ocount,
                                                const int* __restrict__ olist,
                                                const float* __restrict__ basef,
                                                const float* __restrict__ Wo,
                                                const float* __restrict__ boL,
                                                const float* __restrict__ biasL,
                                                const float* __restrict__ x,
                                                float* __restrict__ cur,
                                                float* __restrict__ rx) {
    __shared__ float basL[8][256];
    int t = threadIdx.x;
    int dt = blockIdx.y;
    int nit = work[63];

    for (int j = blockIdx.x; j < nit; j += 32) {
        int wi = work[j];
        int o = wi >> 8;
        int c0 = (wi & 255) * 8;
        int cnt = ocount[o];
        int rem = cnt - c0;
        if (rem > 8) rem = 8;

        int bidx[8];
#pragma unroll
        for (int g = 0; g < 8; ++g) {
            int idx = c0 + g;
            if (idx >= cnt) idx = cnt - 1;   // pad with duplicate (not written back)
            bidx[g] = olist[o * 256 + idx];
        }
        __syncthreads();   // protect basL from previous item's readers
#pragma unroll
        for (int g = 0; g < 8; ++g) basL[g][t] = basef[bidx[g] * H_ + t];
        __syncthreads();

        int d = dt * 256 + t;
        const float* wp = Wo + (size_t)o * D_ + d;
        size_t nn = (size_t)o * D_ + d;
        float bov = boL[nn];
        float biv = biasL[nn];

        float acc[8] = {0.f, 0.f, 0.f, 0.f, 0.f, 0.f, 0.f, 0.f};
        for (int k0 = 0; k0 < 256; k0 += 8) {
            float w[8];
#pragma unroll
            for (int u = 0; u < 8; ++u) w[u] = wp[(size_t)(k0 + u) * OD_];
#pragma unroll
            for (int h = 0; h < 2; ++h) {
                int kb = k0 + h * 4;
                f32x4 bv[8];
#pragma unroll
                for (int g = 0; g < 8; ++g) bv[g] = *(const f32x4*)&basL[g][kb];
#pragma unroll
                for (int u = 0; u < 4; ++u) {
                    float wu = w[h * 4 + u];
#pragma unroll
                    for (int g = 0; g < 8; ++g) acc[g] += bv[g][u] * wu;   // k ascending
                }
            }
        }
#pragma unroll
        for (int g = 0; g < 8; ++g) {
            if (g < rem) {
                int b = bidx[g];
                float outv = cur[b * D_ + d] + acc[g] + bov + biv;
                cur[b * D_ + d] = outv;
                rx[b * D_ + d] = outv - x[b * D_ + d];
            }
        }
    }
}

// ---------------------------------------------------------------------------
extern "C" void kernel_launch(void* const* d_in, const int* in_sizes, int n_in,
                              void* d_out, int out_size, void* d_ws, size_t ws_size,
                              hipStream_t stream) {
    const float* x    = (const float*)d_in[0];  // [256][3072]
    const float* Wb   = (const float*)d_in[1];  // [3072][256]
    const float* bb   = (const float*)d_in[2];  // [256]
    const float* Wo   = (const float*)d_in[3];  // [4][256][98304]
    const float* bo   = (const float*)d_in[4];  // [4][98304]
    const float* bias = (const float*)d_in[5];  // [4][32][3072]

    float* out = (float*)d_out;
    float* enc = out;            // [256][4] (indices as float)
    float* cur = out + 1024;     // [256][3072] reconstruction

    float* ws = (float*)d_ws;
    float* zpart   = ws;                          // 16*256*256 = 1048576
    float* partial = ws + 1048576;                // 256*32*48  = 393216
    float* rx      = ws + 1441792;                // 256*3072   = 786432
    float* basef   = ws + 2228224;                // 256*256    = 65536
    unsigned char* base_ready = (unsigned char*)(ws + 2293760);  // 163840 B
    int* idxbuf    = (int*)(ws + 2334720);        // 256 ints
    int* ocount    = (int*)(ws + 2334976);        // 32 ints
    int* olist     = (int*)(ws + 2335008);        // 32*256 ints
    int* work      = (int*)(ws + 2343200);        // 64 ints

    init_kernel<<<512, 256, 0, stream>>>(x, cur, rx, zpart);

    for (int i = 0; i < NL_; ++i) {
        const float* WoL   = Wo + (size_t)i * H_ * OD_;
        const float* boLp  = bo + (size_t)i * OD_;
        const float* biasL = bias + (size_t)i * OD_;
        if (i > 0) gemm1_kernel<<<512, 256, 0, stream>>>(cur, Wb, zpart);
        e_kernel<<<256, 256, 0, stream>>>(zpart, bb, base_ready, basef);
        g2_kernel<<<768, 512, 0, stream>>>(base_ready, WoL, biasL, boLp, rx, partial);
        c_kernel<<<256, 256, 0, stream>>>(partial, idxbuf, enc, i);
        bucket_kernel<<<1, 256, 0, stream>>>(idxbuf, ocount, olist, work);
        d_kernel<<<dim3(32, 12), 256, 0, stream>>>(work, ocount, olist, basef, WoL, boLp, biasL, x, cur, rx);
    }
}